// Round 4
// baseline (375.746 us; speedup 1.0000x reference)
//
#include <hip/hip_runtime.h>
#include <hip/hip_bf16.h>

// CausalDiscoveryModule: B=256, N=512, E=32, IN=512, K=10
// out[b,i,j] = gate_b * sigmoid(logit) on per-(b,i)-row top-10 of j, else 0
// logit = sum_e (c_b^2 * emb_i)[e] * emb_j[e]
//
// R9 (base = R8; occupancy fix):
//  - R8 post-mortem: dense-write epilogue is at the 262MB floor; k2 (~155us)
//    is VALU/latency-bound with only 16 waves/CU (grid 2048 x 2-wave blocks
//    = 8 blk/CU = 50% occ; VALUBusy 62%). Dependent pk_fma chains + serial
//    TOP10_INSERT chains can't be hidden by 4 waves/SIMD.
//  - R9: 4 waves/block (256 thr), each wave scans a j-QUARTER (128 j, 32
//    iters). 8 blk/CU x 4 waves = 32 waves/CU = 100% nominal occupancy.
//    Unlike old R4's regressing 4-way split: LDS kept at 16.4KB (u16 merge
//    indices, rowbuf 2 rows/phase/wave, union'd with merge arrays) so 8
//    blocks/CU still fit; launch_bounds(256,8) caps VGPR at 64 (measured 36
//    -> no spills). 4-list merge in ascending-j order, strict->, preserves
//    exact jax tie order.
//  - e-row loads widened f2 -> nf4 (dwordx2 -> dwordx4): halves VMEM issue
//    count in the hot loop.

#define NUM_VARS 512
#define EMBED_DIM 32
#define IN_DIM 512
#define BATCH 256

typedef float nf4 __attribute__((ext_vector_type(4)));
typedef float f2 __attribute__((ext_vector_type(2)));

// ---------------- K1: context MLP -> w = c^2 [256][32], gate [256] ----------
__global__ __launch_bounds__(256) void cdm_k1(
    const float* __restrict__ ctx, const float* __restrict__ W1,
    const float* __restrict__ b1, const float* __restrict__ W2,
    const float* __restrict__ b2, const float* __restrict__ Wg,
    const float* __restrict__ bg, float* __restrict__ wws,
    float* __restrict__ gws) {
  const int bb = blockIdx.x;
  const int t = threadIdx.x;
  __shared__ float xs[512];
  __shared__ float psum[32][9];   // +1 pad
  __shared__ float hs[32];
  __shared__ float cs[32];
  const float* x = ctx + (bb << 9);
  xs[t] = x[t];
  xs[t + 256] = x[t + 256];
  __syncthreads();
  {
    const int e = t >> 3, part = t & 7;
    const float* wrow = W1 + e * 512 + part * 64;
    const float* xp = xs + part * 64;
    float a = 0.f;
#pragma unroll
    for (int m = 0; m < 64; ++m) a = fmaf(wrow[m], xp[m], a);
    psum[e][part] = a;
  }
  __syncthreads();
  if (t < 32) {
    float a = 0.f;
#pragma unroll
    for (int p = 0; p < 8; ++p) a += psum[t][p];
    hs[t] = fmaxf(a + b1[t], 0.f);
  }
  __syncthreads();
  if (t < 32) {
    const float* wrow = W2 + (t << 5);
    float a = 0.f;
#pragma unroll
    for (int k = 0; k < 32; ++k) a = fmaf(wrow[k], hs[k], a);
    float c = a + b2[t];
    cs[t] = c;
    wws[(bb << 5) + t] = c * c;
  }
  __syncthreads();
  if (t == 0) {
    float a = 0.f;
#pragma unroll
    for (int k = 0; k < 32; ++k) a = fmaf(Wg[k], cs[k], a);
    float g = a + bg[0];
    gws[bb] = 1.f / (1.f + __expf(-g));
  }
}

// strict-> shift insert: equal values keep earlier-inserted (lower j) above
#define TOP10_INSERT(av, aj, v, jn)                           \
  do {                                                        \
    _Pragma("unroll") for (int k = 9; k >= 1; --k) {          \
      bool gk = (v) > av[k];                                  \
      bool gk1 = (v) > av[k - 1];                             \
      av[k] = gk ? (gk1 ? av[k - 1] : (v)) : av[k];           \
      aj[k] = gk ? (gk1 ? aj[k - 1] : (jn)) : aj[k];          \
    }                                                         \
    bool g0 = (v) > av[0];                                    \
    av[0] = g0 ? (v) : av[0];                                 \
    aj[0] = g0 ? (jn) : aj[0];                                \
  } while (0)

// ------- K2: 4-wave block per 64 rows; j-quarter per wave; dense write -----
__global__ __launch_bounds__(256, 8) void cdm_k2(
    const float* __restrict__ emb, const float* __restrict__ wws,
    const float* __restrict__ gws, float* __restrict__ out) {
  const int lane = threadIdx.x & 63;
  const int q = threadIdx.x >> 6;    // wave = j quarter: [128q, 128q+128)
  const int G = __builtin_amdgcn_readfirstlane(blockIdx.x);
  const int r0 = G << 6;             // 64 rows per block, same b
  const int b = r0 >> 9;
  const int i = (r0 + lane) & 511;
  const int jbase = __builtin_amdgcn_readfirstlane(q << 7);

  // union: merge arrays (phase 1) / row-compose buffer (phase 2)
  //   mvv  [4][10][64] f32 @ 0      = 10240 B
  //   mjj  [4][10][64] u16 @ 10240  =  5120 B   (total 15360)
  //   rowbuf [4][2][512] f32 @ 0    = 16384 B
  __shared__ __align__(16) char smem_u[16384];
  float (*mvv)[10][64] = reinterpret_cast<float(*)[10][64]>(smem_u);
  unsigned short (*mjj)[10][64] =
      reinterpret_cast<unsigned short(*)[10][64]>(smem_u + 10240);
  float* rowbuf = reinterpret_cast<float*>(smem_u);

  // sv2[p] = (c^2)[b] * emb[i] as float2 pairs (per-lane)
  f2 sv2[16];
  {
    const f2* wb = reinterpret_cast<const f2*>(wws + (b << 5));
    const f2* ei = reinterpret_cast<const f2*>(emb + (i << 5));
#pragma unroll
    for (int p = 0; p < 16; ++p) sv2[p] = wb[p] * ei[p];
  }
  const float gateb = gws[b];

  float hv[10];
  int hj[10];
#pragma unroll
  for (int k = 0; k < 10; ++k) { hv[k] = -1e30f; hj[k] = 0; }

  const nf4* eb4 = reinterpret_cast<const nf4*>(emb);
  for (int t = 0; t < 32; ++t) {
    const int j0 = jbase + (t << 2);
    const nf4* e0 = eb4 + ((j0 + 0) << 3);   // 8 nf4 per emb row
    const nf4* e1 = eb4 + ((j0 + 1) << 3);
    const nf4* e2 = eb4 + ((j0 + 2) << 3);
    const nf4* e3 = eb4 + ((j0 + 3) << 3);
    f2 c0 = {0.f, 0.f}, c1 = {0.f, 0.f}, c2 = {0.f, 0.f}, c3 = {0.f, 0.f};
#pragma unroll
    for (int p = 0; p < 8; ++p) {
      nf4 v0 = e0[p], v1 = e1[p], v2 = e2[p], v3 = e3[p];
      c0 += sv2[2 * p] * __builtin_shufflevector(v0, v0, 0, 1);
      c0 += sv2[2 * p + 1] * __builtin_shufflevector(v0, v0, 2, 3);
      c1 += sv2[2 * p] * __builtin_shufflevector(v1, v1, 0, 1);
      c1 += sv2[2 * p + 1] * __builtin_shufflevector(v1, v1, 2, 3);
      c2 += sv2[2 * p] * __builtin_shufflevector(v2, v2, 0, 1);
      c2 += sv2[2 * p + 1] * __builtin_shufflevector(v2, v2, 2, 3);
      c3 += sv2[2 * p] * __builtin_shufflevector(v3, v3, 0, 1);
      c3 += sv2[2 * p + 1] * __builtin_shufflevector(v3, v3, 2, 3);
    }
    float a0 = c0.x + c0.y, a1 = c1.x + c1.y;
    float a2 = c2.x + c2.y, a3 = c3.x + c3.y;

    const float thr = hv[9];
    int p0 = a0 > thr, p1 = a1 > thr, p2 = a2 > thr, p3 = a3 > thr;
    while (__any(p0 | p1 | p2 | p3)) {
      if (p0 | p1 | p2 | p3) {
        float v;
        int jn;
        if (p0) { v = a0; jn = j0; p0 = 0; }
        else if (p1) { v = a1; jn = j0 + 1; p1 = 0; }
        else if (p2) { v = a2; jn = j0 + 2; p2 = 0; }
        else { v = a3; jn = j0 + 3; p3 = 0; }
        TOP10_INSERT(hv, hj, v, jn);
      }
      const float nt = hv[9];
      p0 = p0 && (a0 > nt);
      p1 = p1 && (a1 > nt);
      p2 = p2 && (a2 > nt);
      p3 = p3 && (a3 > nt);
    }
  }

  // ---- publish; every wave builds the final merged list ---------------------
#pragma unroll
  for (int k = 0; k < 10; ++k) {
    mvv[q][k][lane] = hv[k];
    mjj[q][k][lane] = (unsigned short)hj[k];
  }
  __syncthreads();

  // merge 4 quarter-lists in ascending-j order (exact jax tie order):
  // base = list 0, then strict-> insert lists 1,2,3.
  float fv[10];
  int fj[10];
#pragma unroll
  for (int k = 0; k < 10; ++k) {
    fv[k] = mvv[0][k][lane];
    fj[k] = (int)mjj[0][k][lane];
  }
#pragma unroll
  for (int m = 1; m < 4; ++m) {
#pragma unroll
    for (int k = 0; k < 10; ++k) {
      float v = mvv[m][k][lane];
      int jn = (int)mjj[m][k][lane];
      if (v > fv[9]) TOP10_INSERT(fv, fj, v, jn);
    }
  }

  float oval[10];
#pragma unroll
  for (int k = 0; k < 10; ++k) oval[k] = gateb / (1.f + __expf(-fv[k]));

  __syncthreads();   // merge-array reads done before overlay reuse

  // ---- epilogue: batched LDS row compose; dense one-pass coalesced write ---
  // Wave q emits rows r0+16q .. r0+16q+15 in 8 phases of 2 rows:
  //   scatter(2 owner lanes x 10 ds_write) | fence | per row: 2x ds_read_b128
  //   + 2x global_store_dwordx4 | fence | rezero | fence
  // Fences are compile-time only (asm "" memory clobber) to stop alias-based
  // reordering of float*-scatter vs nf4*-read (the R6 bug); HW DS order per
  // wave provides visibility.
  float* rbw = rowbuf + (q << 10);          // wave-private [2][512]
  nf4* rbw4 = reinterpret_cast<nf4*>(rbw);  // 256 nf4
  {
    const nf4 z4 = {0.f, 0.f, 0.f, 0.f};
#pragma unroll
    for (int s = 0; s < 4; ++s) rbw4[(s << 6) + lane] = z4;
  }
  asm volatile("" ::: "memory");

  for (int p = 0; p < 8; ++p) {
    const int rbase = (q << 4) | (p << 1);  // block-relative first row (even)
    const bool own = (lane >> 1) == (rbase >> 1);
    const int slot = lane & 1;
    if (own) {
      float* dst = rbw + (slot << 9);
#pragma unroll
      for (int k = 0; k < 10; ++k) dst[fj[k]] = oval[k];
    }
    asm volatile("" ::: "memory");   // scatter before reads
#pragma unroll
    for (int s = 0; s < 2; ++s) {
      nf4 lo = rbw4[(s << 7) + lane];        // floats [0,256) of row s
      nf4 hi = rbw4[(s << 7) + 64 + lane];   // floats [256,512)
      nf4* ob = reinterpret_cast<nf4*>(out + ((size_t)(r0 + rbase + s) << 9));
      ob[lane] = lo;                         // fully coalesced dwordx4
      ob[lane + 64] = hi;
    }
    asm volatile("" ::: "memory");   // reads before rezero
    if (own) {
      float* dst = rbw + (slot << 9);
#pragma unroll
      for (int k = 0; k < 10; ++k) dst[fj[k]] = 0.f;
    }
    asm volatile("" ::: "memory");   // rezero before next phase's scatter
  }
}

extern "C" void kernel_launch(void* const* d_in, const int* in_sizes, int n_in,
                              void* d_out, int out_size, void* d_ws,
                              size_t ws_size, hipStream_t stream) {
  const float* ctx = (const float*)d_in[0];
  const float* emb = (const float*)d_in[1];
  const float* W1 = (const float*)d_in[2];
  const float* b1 = (const float*)d_in[3];
  const float* W2 = (const float*)d_in[4];
  const float* b2 = (const float*)d_in[5];
  const float* Wg = (const float*)d_in[6];
  const float* bg = (const float*)d_in[7];
  float* out = (float*)d_out;
  float* wws = (float*)d_ws;            // 256*32 floats: c^2
  float* gws = wws + BATCH * EMBED_DIM; // 256 floats: gate

  cdm_k1<<<BATCH, 256, 0, stream>>>(ctx, W1, b1, W2, b2, Wg, bg, wws, gws);
  cdm_k2<<<2048, 256, 0, stream>>>(emb, wws, gws, out);
}